// Round 18
// baseline (30.355 us; speedup 1.0000x reference)
//
#include <hip/hip_runtime.h>
#include <hip/hip_bf16.h>

// Problem constants: B=8, T=128, n=127 neighbors, Q=K=64, H=4, O=H*K=256
#define NB 127
#define SCALE 2.885390081777927f   // 2*log2(e): folds tanh's e^{2x} into one exp2

typedef __attribute__((ext_vector_type(8))) short bf16x8;
typedef __attribute__((ext_vector_type(4))) float f32x4;

// ws layout: packed bf16 MFMA fragments, 4 x 32KB (short offsets).
// Wk and Wq are PRE-SCALED by SCALE in the pack kernel.
#define WKP_S  0
#define WVP_S  16384
#define WQP_S  32768
#define WVQP_S 49152
#define WS_NEEDED ((size_t)(4 * 16384 * 2))

__device__ __forceinline__ short bfs(float f) {
  __hip_bfloat16 h = __float2bfloat16(f);
  return __builtin_bit_cast(short, h);
}
__device__ __forceinline__ unsigned packbf2(float a, float b) {
  unsigned lo = (unsigned short)bfs(a);
  unsigned hi = (unsigned short)bfs(b);
  return lo | (hi << 16);
}
__device__ __forceinline__ float b2f(short s) {
  unsigned u = ((unsigned)(unsigned short)s) << 16;
  return __builtin_bit_cast(float, u);
}
__device__ __forceinline__ bf16x8 gath_s(const float* __restrict__ p, float s) {
  float4 a = *(const float4*)p;
  float4 b = *(const float4*)(p + 4);
  bf16x8 f;
  f[0] = bfs(a.x * s); f[1] = bfs(a.y * s); f[2] = bfs(a.z * s); f[3] = bfs(a.w * s);
  f[4] = bfs(b.x * s); f[5] = bfs(b.y * s); f[6] = bfs(b.z * s); f[7] = bfs(b.w * s);
  return f;
}
// sigmoid-like term: 1/(exp2(x)+1)
__device__ __forceinline__ float sigt(float x) {
  return __builtin_amdgcn_rcpf(__builtin_amdgcn_exp2f(x) + 1.f);
}

// ================= pack kernel (grid 64): coalesced f32 reads -> fragment-order bf16 ====
__global__ __launch_bounds__(256, 2) void
pack_kernel(const float* __restrict__ Wk, const float* __restrict__ Wq,
            const float* __restrict__ Wv, short* __restrict__ dstall)
{
  const int blk = blockIdx.x;
  const int tid = threadIdx.x;
  const int m = blk >> 4, sub = blk & 15;
  const float* src; int stride, off, dsto; float scl;
  if (m == 0)      { src = Wk; stride = 64;  off = 0;  dsto = WKP_S;  scl = SCALE; }
  else if (m == 1) { src = Wv; stride = 128; off = 0;  dsto = WVP_S;  scl = 1.f; }  // Wv kv
  else if (m == 2) { src = Wq; stride = 64;  off = 0;  dsto = WQP_S;  scl = SCALE; }
  else             { src = Wv; stride = 128; off = 64; dsto = WVQP_S; scl = 1.f; }  // Wv q
  short* dst = dstall + dsto;
  int i4 = sub * 256 + tid;               // float4 index in 256x64 submatrix
  int o = i4 >> 4, c4 = i4 & 15;
  float4 v = ((const float4*)(src + o * stride + off))[c4];
  int k0 = c4 * 4;
  int kt = k0 >> 5, gg = (k0 & 31) >> 3, j0 = k0 & 7;
  int head = o >> 6, nt = (o >> 4) & 3, ol = o & 15;
  int di = ((((head * 4 + nt) * 2 + kt) * 64) + gg * 16 + ol) * 8 + j0;
  *(uint2*)(dst + di) = make_uint2(packbf2(v.x * scl, v.y * scl),
                                   packbf2(v.z * scl, v.w * scl));
}

// ================= main kernel (grid 512, 2 bt/block, wave = head) =================
// R17 fused per-bt pipeline (proven correct, spill-free at (256,2)) + block-level
// double buffering: bt1's global loads are ISSUED before bt0's compute (T14
// issue-early/write-late), so bt1's HBM latency hides under bt0's fused sweep.
// All 512 blocks co-resident in one dispatch round (2/CU).
template <int PREP>
__global__ __launch_bounds__(256, 2) void
rnn_attn_kernel(const float* __restrict__ q_x, const float* __restrict__ kv_x,
                const float* __restrict__ Wk, const float* __restrict__ Wq,
                const float* __restrict__ Wv, const float* __restrict__ bv,
                const float* __restrict__ bias, const float* __restrict__ wsc,
                const short* __restrict__ pack, float* __restrict__ out)
{
  __shared__ __align__(16) unsigned char Atile[2][128 * 128];   // 32 KB, double-buffered
  __shared__ float4 qv_lds[4][4][4];   // wave-private slots -> safe to reuse per bt

  const int tid = threadIdx.x;
  const int bt0 = blockIdx.x * 2;
  const int lane = tid & 63;
  const int head = tid >> 6;
  const int l15 = lane & 15;
  const int g = lane >> 4;

  // ---- per-bt fused pipeline (R17 verbatim, tile base parameterized) ----
  auto do_bt = [&](int bt, const unsigned char* __restrict__ tile) {
    // prologue: qq/qv via broadcast-B MFMA
    f32x4 qq[4];
    {
      bf16x8 qf0 = gath_s(q_x + bt * 64 + g * 8, 1.f);
      bf16x8 qf1 = gath_s(q_x + bt * 64 + 32 + g * 8, 1.f);
      #pragma unroll
      for (int nt = 0; nt < 4; ++nt) {
        bf16x8 wv0, wv1;
        if (PREP) {
          const bf16x8* pv = (const bf16x8*)(pack + WVQP_S);
          wv0 = pv[((head * 4 + nt) * 2 + 0) * 64 + lane];
          wv1 = pv[((head * 4 + nt) * 2 + 1) * 64 + lane];
        } else {
          int o = head * 64 + nt * 16 + l15;
          wv0 = gath_s(Wv + o * 128 + 64 + g * 8, 1.f);
          wv1 = gath_s(Wv + o * 128 + 64 + 32 + g * 8, 1.f);
        }
        float4 bv4 = ((const float4*)(bv + head * 64))[nt * 4 + g];
        f32x4 b = (f32x4){bv4.x, bv4.y, bv4.z, bv4.w};
        b = __builtin_amdgcn_mfma_f32_16x16x32_bf16(wv0, qf0, b, 0, 0, 0);
        b = __builtin_amdgcn_mfma_f32_16x16x32_bf16(wv1, qf1, b, 0, 0, 0);
        if (l15 == 0) qv_lds[head][nt][g] = make_float4(b[0], b[1], b[2], b[3]);
      }
      #pragma unroll
      for (int nt = 0; nt < 4; ++nt) {
        bf16x8 wq0, wq1;
        if (PREP) {
          const bf16x8* pw = (const bf16x8*)(pack + WQP_S);
          wq0 = pw[((head * 4 + nt) * 2 + 0) * 64 + lane];
          wq1 = pw[((head * 4 + nt) * 2 + 1) * 64 + lane];
        } else {
          int o = head * 64 + nt * 16 + l15;
          wq0 = gath_s(Wq + o * 64 + g * 8, SCALE);
          wq1 = gath_s(Wq + o * 64 + 32 + g * 8, SCALE);
        }
        float4 bs4 = ((const float4*)bias)[nt * 4 + g];
        f32x4 a = (f32x4){bs4.x * SCALE, bs4.y * SCALE, bs4.z * SCALE, bs4.w * SCALE};
        a = __builtin_amdgcn_mfma_f32_16x16x32_bf16(wq0, qf0, a, 0, 0, 0);
        a = __builtin_amdgcn_mfma_f32_16x16x32_bf16(wq1, qf1, a, 0, 0, 0);
        qq[nt] = a;
      }
    }

    // score weights + all four Wk fragment pairs
    f32x4 ws4[4];
    bf16x8 bk[4][2];
    #pragma unroll
    for (int nt = 0; nt < 4; ++nt) {
      float4 t = ((const float4*)wsc)[nt * 4 + g];
      ws4[nt] = (f32x4){-2.f * t.x, -2.f * t.y, -2.f * t.z, -2.f * t.w};
      if (PREP) {
        const bf16x8* pw = (const bf16x8*)(pack + WKP_S);
        bk[nt][0] = pw[((head * 4 + nt) * 2 + 0) * 64 + lane];
        bk[nt][1] = pw[((head * 4 + nt) * 2 + 1) * 64 + lane];
      } else {
        int o = head * 64 + nt * 16 + l15;
        bk[nt][0] = gath_s(Wk + o * 64 + g * 8, SCALE);
        bk[nt][1] = gath_s(Wk + o * 64 + 32 + g * 8, SCALE);
      }
    }

    // fused sweep: score -> unnormalized softmax -> pv accumulate
    float pvp0[8], pvp1[8], z = 0.f;
    #pragma unroll
    for (int j = 0; j < 8; ++j) { pvp0[j] = 0.f; pvp1[j] = 0.f; }
    #pragma unroll 1
    for (int mt = 0; mt < 8; ++mt) {
      int row = mt * 16 + l15;
      int byte0 = (row << 7) + g * 16;
      int swz = (l15 & 7) << 4;
      bf16x8 a0 = *(const bf16x8*)(tile + (byte0 ^ swz));
      bf16x8 a1 = *(const bf16x8*)(tile + ((byte0 + 64) ^ swz));
      float pp0, pp1, pp2, pp3;
      {
        f32x4 acc = qq[0];
        acc = __builtin_amdgcn_mfma_f32_16x16x32_bf16(bk[0][0], a0, acc, 0, 0, 0);
        acc = __builtin_amdgcn_mfma_f32_16x16x32_bf16(bk[0][1], a1, acc, 0, 0, 0);
        pp0 = ws4[0][0] * sigt(acc[0]);
        pp0 = fmaf(ws4[0][1], sigt(acc[1]), pp0);
        pp0 = fmaf(ws4[0][2], sigt(acc[2]), pp0);
        pp0 = fmaf(ws4[0][3], sigt(acc[3]), pp0);
      }
      {
        f32x4 acc = qq[1];
        acc = __builtin_amdgcn_mfma_f32_16x16x32_bf16(bk[1][0], a0, acc, 0, 0, 0);
        acc = __builtin_amdgcn_mfma_f32_16x16x32_bf16(bk[1][1], a1, acc, 0, 0, 0);
        pp1 = ws4[1][0] * sigt(acc[0]);
        pp1 = fmaf(ws4[1][1], sigt(acc[1]), pp1);
        pp1 = fmaf(ws4[1][2], sigt(acc[2]), pp1);
        pp1 = fmaf(ws4[1][3], sigt(acc[3]), pp1);
      }
      {
        f32x4 acc = qq[2];
        acc = __builtin_amdgcn_mfma_f32_16x16x32_bf16(bk[2][0], a0, acc, 0, 0, 0);
        acc = __builtin_amdgcn_mfma_f32_16x16x32_bf16(bk[2][1], a1, acc, 0, 0, 0);
        pp2 = ws4[2][0] * sigt(acc[0]);
        pp2 = fmaf(ws4[2][1], sigt(acc[1]), pp2);
        pp2 = fmaf(ws4[2][2], sigt(acc[2]), pp2);
        pp2 = fmaf(ws4[2][3], sigt(acc[3]), pp2);
      }
      {
        f32x4 acc = qq[3];
        acc = __builtin_amdgcn_mfma_f32_16x16x32_bf16(bk[3][0], a0, acc, 0, 0, 0);
        acc = __builtin_amdgcn_mfma_f32_16x16x32_bf16(bk[3][1], a1, acc, 0, 0, 0);
        pp3 = ws4[3][0] * sigt(acc[0]);
        pp3 = fmaf(ws4[3][1], sigt(acc[1]), pp3);
        pp3 = fmaf(ws4[3][2], sigt(acc[2]), pp3);
        pp3 = fmaf(ws4[3][3], sigt(acc[3]), pp3);
      }
      float p = (pp0 + pp1) + (pp2 + pp3);
      p += __shfl_xor(p, 16);    // full score for row n = mt*16+l15, all lanes
      p += __shfl_xor(p, 32);
      float e = __expf(p);       // |p| <= Sigma|ws| ~ 2.6 -> safe without max
      if (mt == 7 && l15 == 15) e = 0.f;   // pad row n=127
      z += e;
      #pragma unroll
      for (int j = 0; j < 8; ++j) {
        pvp0[j] = fmaf(e, b2f(a0[j]), pvp0[j]);
        pvp1[j] = fmaf(e, b2f(a1[j]), pvp1[j]);
      }
    }

    // z holds only this lane's 8 rows -> reduce across l15
    z += __shfl_xor(z, 1);
    z += __shfl_xor(z, 2);
    z += __shfl_xor(z, 4);
    z += __shfl_xor(z, 8);
    float rz = __builtin_amdgcn_rcpf(z);

    bf16x8 pa0, pa1;
    #pragma unroll
    for (int j = 0; j < 8; ++j) { pa0[j] = bfs(pvp0[j] * rz); pa1[j] = bfs(pvp1[j] * rz); }

    // GEMV: out[o] = sum_k pv[k]*Wv_kv[o,k]; MFMA i-dim folds the 16 partials
    float tt[4];
    #pragma unroll 2
    for (int nt = 0; nt < 4; ++nt) {
      bf16x8 bw0, bw1;
      if (PREP) {
        const bf16x8* pw = (const bf16x8*)(pack + WVP_S);
        bw0 = pw[((head * 4 + nt) * 2 + 0) * 64 + lane];
        bw1 = pw[((head * 4 + nt) * 2 + 1) * 64 + lane];
      } else {
        int o = head * 64 + nt * 16 + l15;
        bw0 = gath_s(Wv + o * 128 + g * 8, 1.f);
        bw1 = gath_s(Wv + o * 128 + 32 + g * 8, 1.f);
      }
      f32x4 c = (f32x4){0.f, 0.f, 0.f, 0.f};
      c = __builtin_amdgcn_mfma_f32_16x16x32_bf16(pa0, bw0, c, 0, 0, 0);
      c = __builtin_amdgcn_mfma_f32_16x16x32_bf16(pa1, bw1, c, 0, 0, 0);
      float t = (c[0] + c[1]) + (c[2] + c[3]);
      t += __shfl_xor(t, 16);
      t += __shfl_xor(t, 32);
      tt[nt] = t;            // out-partial for o = nt*16 + l15, valid in all lanes
    }

    float v = tt[0];
    v = (g == 1) ? tt[1] : v;
    v = (g == 2) ? tt[2] : v;
    v = (g == 3) ? tt[3] : v;
    float qv = ((const float*)&qv_lds[head][g][l15 >> 2])[l15 & 3];
    out[bt * 256 + head * 64 + lane] = v + qv;
  };

  // ---- stage bt0 directly into buf0 (coalesced, XOR-swizzled) ----
  {
    const float* kv = kv_x + (size_t)bt0 * (NB * 64);
    #pragma unroll
    for (int i = 0; i < 8; ++i) {
      int idx = i * 256 + tid;
      int row = idx >> 4, c = idx & 15;
      float4 v = (row < NB) ? ((const float4*)kv)[idx] : make_float4(0.f, 0.f, 0.f, 0.f);
      int byte = ((row << 7) + (c << 3)) ^ ((row & 7) << 4);
      *(uint2*)(&Atile[0][byte]) = make_uint2(packbf2(v.x, v.y), packbf2(v.z, v.w));
    }
  }

  // ---- ISSUE bt1's global loads now (latency hides under bt0's compute) ----
  float4 pf[8];
  {
    const float* kv = kv_x + (size_t)(bt0 + 1) * (NB * 64);
    #pragma unroll
    for (int i = 0; i < 8; ++i) {
      int idx = i * 256 + tid;
      int row = idx >> 4;
      pf[i] = (row < NB) ? ((const float4*)kv)[idx] : make_float4(0.f, 0.f, 0.f, 0.f);
    }
  }

  __syncthreads();   // buf0 ready

  do_bt(bt0, &Atile[0][0]);          // compute + store bt0 (pf loads in flight)

  // ---- write prefetched bt1 tile into buf1 ----
  #pragma unroll
  for (int i = 0; i < 8; ++i) {
    int idx = i * 256 + tid;
    int row = idx >> 4, c = idx & 15;
    int byte = ((row << 7) + (c << 3)) ^ ((row & 7) << 4);
    *(uint2*)(&Atile[1][byte]) = make_uint2(packbf2(pf[i].x, pf[i].y),
                                            packbf2(pf[i].z, pf[i].w));
  }
  __syncthreads();   // buf1 ready

  do_bt(bt0 + 1, &Atile[1][0]);      // compute + store bt1
}

extern "C" void kernel_launch(void* const* d_in, const int* in_sizes, int n_in,
                              void* d_out, int out_size, void* d_ws, size_t ws_size,
                              hipStream_t stream) {
  const float* q_x  = (const float*)d_in[0];
  const float* kv_x = (const float*)d_in[1];
  const float* Wk   = (const float*)d_in[2];
  const float* Wq   = (const float*)d_in[3];
  const float* Wv   = (const float*)d_in[4];
  const float* bv   = (const float*)d_in[5];
  const float* bias = (const float*)d_in[6];
  const float* wsc  = (const float*)d_in[7];
  // d_in[8] = bs: constant across neighbors -> cancels in softmax, unused.
  float* out = (float*)d_out;
  short* pack = (short*)d_ws;

  if (ws_size >= WS_NEEDED) {
    pack_kernel<<<64, 256, 0, stream>>>(Wk, Wq, Wv, pack);
    rnn_attn_kernel<1><<<512, 256, 0, stream>>>(q_x, kv_x, Wk, Wq, Wv, bv, bias, wsc, pack, out);
  } else {
    rnn_attn_kernel<0><<<512, 256, 0, stream>>>(q_x, kv_x, Wk, Wq, Wv, bv, bias, wsc, pack, out);
  }
}

// Round 19
// 27.984 us; speedup vs baseline: 1.0847x; 1.0847x over previous
//
#include <hip/hip_runtime.h>
#include <hip/hip_bf16.h>

// Problem constants: B=8, T=128, n=127 neighbors, Q=K=64, H=4, O=H*K=256
#define NB 127
#define SCALE 2.885390081777927f   // 2*log2(e): folds tanh's e^{2x} into one exp2
#define L2E 1.4426950408889634f    // log2(e): folds softmax exp into exp2

typedef __attribute__((ext_vector_type(8))) short bf16x8;
typedef __attribute__((ext_vector_type(4))) float f32x4;

// ws layout: packed bf16 MFMA fragments, 4 x 32KB (short offsets).
// Wk and Wq are PRE-SCALED by SCALE in the pack kernel.
#define WKP_S  0
#define WVP_S  16384
#define WQP_S  32768
#define WVQP_S 49152
#define WS_NEEDED ((size_t)(4 * 16384 * 2))

__device__ __forceinline__ short bfs(float f) {
  __hip_bfloat16 h = __float2bfloat16(f);
  return __builtin_bit_cast(short, h);
}
__device__ __forceinline__ unsigned packbf2(float a, float b) {
  unsigned lo = (unsigned short)bfs(a);
  unsigned hi = (unsigned short)bfs(b);
  return lo | (hi << 16);
}
__device__ __forceinline__ float b2f(short s) {
  unsigned u = ((unsigned)(unsigned short)s) << 16;
  return __builtin_bit_cast(float, u);
}
__device__ __forceinline__ bf16x8 gath_s(const float* __restrict__ p, float s) {
  float4 a = *(const float4*)p;
  float4 b = *(const float4*)(p + 4);
  bf16x8 f;
  f[0] = bfs(a.x * s); f[1] = bfs(a.y * s); f[2] = bfs(a.z * s); f[3] = bfs(a.w * s);
  f[4] = bfs(b.x * s); f[5] = bfs(b.y * s); f[6] = bfs(b.z * s); f[7] = bfs(b.w * s);
  return f;
}
// sigmoid-like term: 1/(exp2(x)+1)
__device__ __forceinline__ float sigt(float x) {
  return __builtin_amdgcn_rcpf(__builtin_amdgcn_exp2f(x) + 1.f);
}

// ================= pack kernel (grid 64): coalesced f32 reads -> fragment-order bf16 ====
__global__ __launch_bounds__(256, 2) void
pack_kernel(const float* __restrict__ Wk, const float* __restrict__ Wq,
            const float* __restrict__ Wv, short* __restrict__ dstall)
{
  const int blk = blockIdx.x;
  const int tid = threadIdx.x;
  const int m = blk >> 4, sub = blk & 15;
  const float* src; int stride, off, dsto; float scl;
  if (m == 0)      { src = Wk; stride = 64;  off = 0;  dsto = WKP_S;  scl = SCALE; }
  else if (m == 1) { src = Wv; stride = 128; off = 0;  dsto = WVP_S;  scl = 1.f; }  // Wv kv
  else if (m == 2) { src = Wq; stride = 64;  off = 0;  dsto = WQP_S;  scl = SCALE; }
  else             { src = Wv; stride = 128; off = 64; dsto = WVQP_S; scl = 1.f; }  // Wv q
  short* dst = dstall + dsto;
  int i4 = sub * 256 + tid;               // float4 index in 256x64 submatrix
  int o = i4 >> 4, c4 = i4 & 15;
  float4 v = ((const float4*)(src + o * stride + off))[c4];
  int k0 = c4 * 4;
  int kt = k0 >> 5, gg = (k0 & 31) >> 3, j0 = k0 & 7;
  int head = o >> 6, nt = (o >> 4) & 3, ol = o & 15;
  int di = ((((head * 4 + nt) * 2 + kt) * 64) + gg * 16 + ol) * 8 + j0;
  *(uint2*)(dst + di) = make_uint2(packbf2(v.x * scl, v.y * scl),
                                   packbf2(v.z * scl, v.w * scl));
}

// ================= main kernel (grid 1024, wave = head) =================
// R17 fused single-sweep structure (proven 28.0us) with TWO deltas:
//  1. __launch_bounds__(256,3): cap ~170 (sweep peak liveness ~120, margin kept)
//     -> 3 blocks/CU, 12 waves/CU for latency braiding. Spill tripwire: WRITE_SIZE.
//  2. softmax exp via exp2 (ws4 pre-scaled by log2(e)) — one fewer dependent mul.
template <int PREP>
__global__ __launch_bounds__(256, 3) void
rnn_attn_kernel(const float* __restrict__ q_x, const float* __restrict__ kv_x,
                const float* __restrict__ Wk, const float* __restrict__ Wq,
                const float* __restrict__ Wv, const float* __restrict__ bv,
                const float* __restrict__ bias, const float* __restrict__ wsc,
                const short* __restrict__ pack, float* __restrict__ out)
{
  __shared__ __align__(16) unsigned char Atile[128 * 128];
  __shared__ float4 qv_lds[4][4][4];   // [head][nt][g] : qv[o = nt*16+g*4+r]

  const int tid = threadIdx.x;
  const int bt = blockIdx.x;
  const int lane = tid & 63;
  const int head = tid >> 6;
  const int l15 = lane & 15;
  const int g = lane >> 4;

  // ---- stage kv tile (127x64 f32 -> bf16, XOR-swizzled), coalesced ----
  const float* kv = kv_x + (size_t)bt * (NB * 64);
  #pragma unroll
  for (int i = 0; i < 8; ++i) {
    int idx = i * 256 + tid;
    int row = idx >> 4, c = idx & 15;
    float4 v = (row < NB) ? ((const float4*)kv)[idx] : make_float4(0.f, 0.f, 0.f, 0.f);
    int byte = (row << 7) + (c << 3);
    byte ^= ((row & 7) << 4);
    *(uint2*)(&Atile[byte]) = make_uint2(packbf2(v.x, v.y), packbf2(v.z, v.w));
  }

  // ---- prologue: qq/qv via broadcast-B MFMA ----
  f32x4 qq[4];
  {
    bf16x8 qf0 = gath_s(q_x + bt * 64 + g * 8, 1.f);
    bf16x8 qf1 = gath_s(q_x + bt * 64 + 32 + g * 8, 1.f);
    #pragma unroll
    for (int nt = 0; nt < 4; ++nt) {
      bf16x8 wv0, wv1;
      if (PREP) {
        const bf16x8* pv = (const bf16x8*)(pack + WVQP_S);
        wv0 = pv[((head * 4 + nt) * 2 + 0) * 64 + lane];
        wv1 = pv[((head * 4 + nt) * 2 + 1) * 64 + lane];
      } else {
        int o = head * 64 + nt * 16 + l15;
        wv0 = gath_s(Wv + o * 128 + 64 + g * 8, 1.f);
        wv1 = gath_s(Wv + o * 128 + 64 + 32 + g * 8, 1.f);
      }
      float4 bv4 = ((const float4*)(bv + head * 64))[nt * 4 + g];
      f32x4 b = (f32x4){bv4.x, bv4.y, bv4.z, bv4.w};
      b = __builtin_amdgcn_mfma_f32_16x16x32_bf16(wv0, qf0, b, 0, 0, 0);
      b = __builtin_amdgcn_mfma_f32_16x16x32_bf16(wv1, qf1, b, 0, 0, 0);
      if (l15 == 0) qv_lds[head][nt][g] = make_float4(b[0], b[1], b[2], b[3]);
    }
    #pragma unroll
    for (int nt = 0; nt < 4; ++nt) {
      bf16x8 wq0, wq1;
      if (PREP) {
        const bf16x8* pw = (const bf16x8*)(pack + WQP_S);
        wq0 = pw[((head * 4 + nt) * 2 + 0) * 64 + lane];
        wq1 = pw[((head * 4 + nt) * 2 + 1) * 64 + lane];
      } else {
        int o = head * 64 + nt * 16 + l15;
        wq0 = gath_s(Wq + o * 64 + g * 8, SCALE);
        wq1 = gath_s(Wq + o * 64 + 32 + g * 8, SCALE);
      }
      float4 bs4 = ((const float4*)bias)[nt * 4 + g];
      f32x4 a = (f32x4){bs4.x * SCALE, bs4.y * SCALE, bs4.z * SCALE, bs4.w * SCALE};
      a = __builtin_amdgcn_mfma_f32_16x16x32_bf16(wq0, qf0, a, 0, 0, 0);
      a = __builtin_amdgcn_mfma_f32_16x16x32_bf16(wq1, qf1, a, 0, 0, 0);
      qq[nt] = a;
    }
  }

  // ---- score weights (pre-scaled -2*log2e: softmax via exp2) + all Wk frags ----
  f32x4 ws4[4];
  bf16x8 bk[4][2];
  #pragma unroll
  for (int nt = 0; nt < 4; ++nt) {
    float4 t = ((const float4*)wsc)[nt * 4 + g];
    ws4[nt] = (f32x4){-2.f * L2E * t.x, -2.f * L2E * t.y,
                      -2.f * L2E * t.z, -2.f * L2E * t.w};
    if (PREP) {
      const bf16x8* pw = (const bf16x8*)(pack + WKP_S);
      bk[nt][0] = pw[((head * 4 + nt) * 2 + 0) * 64 + lane];
      bk[nt][1] = pw[((head * 4 + nt) * 2 + 1) * 64 + lane];
    } else {
      int o = head * 64 + nt * 16 + l15;
      bk[nt][0] = gath_s(Wk + o * 64 + g * 8, SCALE);
      bk[nt][1] = gath_s(Wk + o * 64 + 32 + g * 8, SCALE);
    }
  }

  __syncthreads();   // the only barrier

  // ---- FUSED sweep: score -> unnormalized softmax (exp2) -> pv accumulate ----
  float pvp0[8], pvp1[8], z = 0.f;
  #pragma unroll
  for (int j = 0; j < 8; ++j) { pvp0[j] = 0.f; pvp1[j] = 0.f; }
  #pragma unroll 1
  for (int mt = 0; mt < 8; ++mt) {
    int row = mt * 16 + l15;
    int byte0 = (row << 7) + g * 16;
    int swz = (l15 & 7) << 4;
    bf16x8 a0 = *(const bf16x8*)(&Atile[byte0 ^ swz]);
    bf16x8 a1 = *(const bf16x8*)(&Atile[(byte0 + 64) ^ swz]);
    float pp0, pp1, pp2, pp3;
    {
      f32x4 acc = qq[0];
      acc = __builtin_amdgcn_mfma_f32_16x16x32_bf16(bk[0][0], a0, acc, 0, 0, 0);
      acc = __builtin_amdgcn_mfma_f32_16x16x32_bf16(bk[0][1], a1, acc, 0, 0, 0);
      pp0 = ws4[0][0] * sigt(acc[0]);
      pp0 = fmaf(ws4[0][1], sigt(acc[1]), pp0);
      pp0 = fmaf(ws4[0][2], sigt(acc[2]), pp0);
      pp0 = fmaf(ws4[0][3], sigt(acc[3]), pp0);
    }
    {
      f32x4 acc = qq[1];
      acc = __builtin_amdgcn_mfma_f32_16x16x32_bf16(bk[1][0], a0, acc, 0, 0, 0);
      acc = __builtin_amdgcn_mfma_f32_16x16x32_bf16(bk[1][1], a1, acc, 0, 0, 0);
      pp1 = ws4[1][0] * sigt(acc[0]);
      pp1 = fmaf(ws4[1][1], sigt(acc[1]), pp1);
      pp1 = fmaf(ws4[1][2], sigt(acc[2]), pp1);
      pp1 = fmaf(ws4[1][3], sigt(acc[3]), pp1);
    }
    {
      f32x4 acc = qq[2];
      acc = __builtin_amdgcn_mfma_f32_16x16x32_bf16(bk[2][0], a0, acc, 0, 0, 0);
      acc = __builtin_amdgcn_mfma_f32_16x16x32_bf16(bk[2][1], a1, acc, 0, 0, 0);
      pp2 = ws4[2][0] * sigt(acc[0]);
      pp2 = fmaf(ws4[2][1], sigt(acc[1]), pp2);
      pp2 = fmaf(ws4[2][2], sigt(acc[2]), pp2);
      pp2 = fmaf(ws4[2][3], sigt(acc[3]), pp2);
    }
    {
      f32x4 acc = qq[3];
      acc = __builtin_amdgcn_mfma_f32_16x16x32_bf16(bk[3][0], a0, acc, 0, 0, 0);
      acc = __builtin_amdgcn_mfma_f32_16x16x32_bf16(bk[3][1], a1, acc, 0, 0, 0);
      pp3 = ws4[3][0] * sigt(acc[0]);
      pp3 = fmaf(ws4[3][1], sigt(acc[1]), pp3);
      pp3 = fmaf(ws4[3][2], sigt(acc[2]), pp3);
      pp3 = fmaf(ws4[3][3], sigt(acc[3]), pp3);
    }
    float p = (pp0 + pp1) + (pp2 + pp3);
    p += __shfl_xor(p, 16);    // full (log2-domain) score for row, all lanes
    p += __shfl_xor(p, 32);
    // unnormalized softmax weight; |p| bounded by log2e*Sigma|ws| -> safe
    float e = __builtin_amdgcn_exp2f(p);
    if (mt == 7 && l15 == 15) e = 0.f;   // pad row n=127
    z += e;
    #pragma unroll
    for (int j = 0; j < 8; ++j) {
      pvp0[j] = fmaf(e, b2f(a0[j]), pvp0[j]);
      pvp1[j] = fmaf(e, b2f(a1[j]), pvp1[j]);
    }
  }

  // ---- z holds only this lane's 8 rows -> reduce across l15 ----
  z += __shfl_xor(z, 1);
  z += __shfl_xor(z, 2);
  z += __shfl_xor(z, 4);
  z += __shfl_xor(z, 8);
  float rz = __builtin_amdgcn_rcpf(z);

  // ---- normalize and convert pvp to an A-fragment ----
  bf16x8 pa0, pa1;
  #pragma unroll
  for (int j = 0; j < 8; ++j) { pa0[j] = bfs(pvp0[j] * rz); pa1[j] = bfs(pvp1[j] * rz); }

  // ---- GEMV: out[o] = sum_k pv[k]*Wv_kv[o,k]; MFMA i-dim folds the 16 partials ----
  float tt[4];
  #pragma unroll 1
  for (int nt = 0; nt < 4; ++nt) {
    bf16x8 bw0, bw1;
    if (PREP) {
      const bf16x8* pw = (const bf16x8*)(pack + WVP_S);
      bw0 = pw[((head * 4 + nt) * 2 + 0) * 64 + lane];
      bw1 = pw[((head * 4 + nt) * 2 + 1) * 64 + lane];
    } else {
      int o = head * 64 + nt * 16 + l15;
      bw0 = gath_s(Wv + o * 128 + g * 8, 1.f);
      bw1 = gath_s(Wv + o * 128 + 32 + g * 8, 1.f);
    }
    f32x4 c = (f32x4){0.f, 0.f, 0.f, 0.f};
    c = __builtin_amdgcn_mfma_f32_16x16x32_bf16(pa0, bw0, c, 0, 0, 0);
    c = __builtin_amdgcn_mfma_f32_16x16x32_bf16(pa1, bw1, c, 0, 0, 0);
    float t = (c[0] + c[1]) + (c[2] + c[3]);
    t += __shfl_xor(t, 16);
    t += __shfl_xor(t, 32);
    tt[nt] = t;            // out-partial for o = nt*16 + l15, valid in all lanes
  }

  // ---- store: lane (l15,g) writes o = g*16 + l15 -> fully coalesced ----
  float v = tt[0];
  v = (g == 1) ? tt[1] : v;
  v = (g == 2) ? tt[2] : v;
  v = (g == 3) ? tt[3] : v;
  float qv = ((const float*)&qv_lds[head][g][l15 >> 2])[l15 & 3];
  out[bt * 256 + head * 64 + lane] = v + qv;
}

extern "C" void kernel_launch(void* const* d_in, const int* in_sizes, int n_in,
                              void* d_out, int out_size, void* d_ws, size_t ws_size,
                              hipStream_t stream) {
  const float* q_x  = (const float*)d_in[0];
  const float* kv_x = (const float*)d_in[1];
  const float* Wk   = (const float*)d_in[2];
  const float* Wq   = (const float*)d_in[3];
  const float* Wv   = (const float*)d_in[4];
  const float* bv   = (const float*)d_in[5];
  const float* bias = (const float*)d_in[6];
  const float* wsc  = (const float*)d_in[7];
  // d_in[8] = bs: constant across neighbors -> cancels in softmax, unused.
  float* out = (float*)d_out;
  short* pack = (short*)d_ws;

  if (ws_size >= WS_NEEDED) {
    pack_kernel<<<64, 256, 0, stream>>>(Wk, Wq, Wv, pack);
    rnn_attn_kernel<1><<<1024, 256, 0, stream>>>(q_x, kv_x, Wk, Wq, Wv, bv, bias, wsc, pack, out);
  } else {
    rnn_attn_kernel<0><<<1024, 256, 0, stream>>>(q_x, kv_x, Wk, Wq, Wv, bv, bias, wsc, pack, out);
  }
}